// Round 1
// baseline (226.668 us; speedup 1.0000x reference)
//
#include <hip/hip_runtime.h>
#include <hip/hip_bf16.h>
#include <math.h>

#define BB 64
#define SS 512
#define DD 1024
#define LL 9

// ---------------- GEMM: logits[row][l] = sum_k inputs[row][k] * W[k][l] + b[l]
// 1024 blocks x 256 threads. Block handles 32 rows. Wave handles 8 rows
// (2 quads of 4). Within a wave: p = lane&15 splits K, sub = lane>>4 picks row.
// W^T staged in LDS (36 KB); 16-lane contiguous float4 reads -> conflict-free,
// sub-groups read the same address -> broadcast. Reduction via DPP row_shr.

#define DPP_ADD(v, ctrl)                                                     \
  v += __int_as_float(__builtin_amdgcn_update_dpp(                           \
      0, __float_as_int(v), ctrl, 0xF, 0xF, false))

__global__ __launch_bounds__(256) void gemm_kernel(
    const float* __restrict__ in, const float* __restrict__ W,
    const float* __restrict__ bias, float* __restrict__ out) {
  __shared__ float Wt[LL][DD];  // 36 KB
  int tid = threadIdx.x;
  for (int i = tid; i < DD * LL; i += 256) {
    int k = i / LL, l = i % LL;  // W is [k][l] row-major
    Wt[l][k] = W[i];
  }
  __syncthreads();

  int lane = tid & 63;
  int wave = tid >> 6;
  int p = lane & 15;
  int sub = lane >> 4;

  int r0 = blockIdx.x * 32 + wave * 8 + sub;  // quad 0
  int r1 = r0 + 4;                            // quad 1
  const float* x0 = in + (size_t)r0 * DD;
  const float* x1 = in + (size_t)r1 * DD;

  float acc0[LL], acc1[LL];
#pragma unroll
  for (int l = 0; l < LL; ++l) { acc0[l] = 0.f; acc1[l] = 0.f; }

  for (int it = 0; it < 16; ++it) {
    int k0 = it * 64 + p * 4;
    float4 w4[LL];
#pragma unroll
    for (int l = 0; l < LL; ++l)
      w4[l] = *reinterpret_cast<const float4*>(&Wt[l][k0]);
    float4 a = *reinterpret_cast<const float4*>(x0 + k0);
    float4 b4 = *reinterpret_cast<const float4*>(x1 + k0);
#pragma unroll
    for (int l = 0; l < LL; ++l) {
      acc0[l] += a.x * w4[l].x + a.y * w4[l].y + a.z * w4[l].z + a.w * w4[l].w;
      acc1[l] += b4.x * w4[l].x + b4.y * w4[l].y + b4.z * w4[l].z + b4.w * w4[l].w;
    }
  }

  // reduce each acc over the 16 lanes of the group; lane p==15 holds the sum
#pragma unroll
  for (int l = 0; l < LL; ++l) {
    DPP_ADD(acc0[l], 0x111);  // row_shr:1
    DPP_ADD(acc0[l], 0x112);  // row_shr:2
    DPP_ADD(acc0[l], 0x114);  // row_shr:4
    DPP_ADD(acc0[l], 0x118);  // row_shr:8
    DPP_ADD(acc1[l], 0x111);
    DPP_ADD(acc1[l], 0x112);
    DPP_ADD(acc1[l], 0x114);
    DPP_ADD(acc1[l], 0x118);
  }
  if (p == 15) {
#pragma unroll
    for (int l = 0; l < LL; ++l) {
      out[(size_t)r0 * LL + l] = acc0[l] + bias[l];
      out[(size_t)r1 * LL + l] = acc1[l] + bias[l];
    }
  }
}

// ---------------- CRF scan in exp-space.
// One batch per 16-lane group (L=9 padded to 16). Lane j holds u[j].
// Step: v[j] = sum_r u[j^r] * Mexp[j^r][j]   (XOR enumeration via ds_swizzle)
//       u'   = v * exp(e_t[j]),  frozen when t >= len.
// Renorm every 8 steps (divide by group max, accumulate log into C).

template <int R>
__device__ inline float swz(float x) {
  return __int_as_float(
      __builtin_amdgcn_ds_swizzle(__float_as_int(x), (R << 10) | 0x1F));
}

__global__ __launch_bounds__(64) void crf_kernel(
    const float* __restrict__ logits, const int* __restrict__ targets,
    const int* __restrict__ seqlen, const float* __restrict__ trans,
    float* __restrict__ out_val) {
  int lane = threadIdx.x;
  int j = lane & 15;
  int g = lane >> 4;
  int b = blockIdx.x * 4 + g;
  int len = seqlen[b];

  float Mx[16];
#pragma unroll
  for (int r = 0; r < 16; ++r) {
    int i = j ^ r;
    Mx[r] = (i < LL && j < LL) ? __expf(trans[i * LL + j]) : 0.f;
  }

  const float* lb = logits + (size_t)b * SS * LL;
  float u = (j < LL) ? __expf(lb[j]) : 0.f;  // t = 0
  float C = 0.f;
  float e_next = (j < LL) ? lb[LL + j] : 0.f;  // t = 1

  for (int t = 1; t < SS; ++t) {
    float e = e_next;
    if (t + 1 < SS) e_next = (j < LL) ? lb[(t + 1) * LL + j] : 0.f;
    float E = (j < LL) ? __expf(e) : 0.f;

    float v = u * Mx[0];
    v += swz<1>(u) * Mx[1];
    v += swz<2>(u) * Mx[2];
    v += swz<3>(u) * Mx[3];
    v += swz<4>(u) * Mx[4];
    v += swz<5>(u) * Mx[5];
    v += swz<6>(u) * Mx[6];
    v += swz<7>(u) * Mx[7];
    v += swz<8>(u) * Mx[8];
    v += swz<9>(u) * Mx[9];
    v += swz<10>(u) * Mx[10];
    v += swz<11>(u) * Mx[11];
    v += swz<12>(u) * Mx[12];
    v += swz<13>(u) * Mx[13];
    v += swz<14>(u) * Mx[14];
    v += swz<15>(u) * Mx[15];

    float un = v * E;
    u = (t < len) ? un : u;

    if ((t & 7) == 0) {
      float m = u;
      m = fmaxf(m, swz<1>(m));
      m = fmaxf(m, swz<2>(m));
      m = fmaxf(m, swz<4>(m));
      m = fmaxf(m, swz<8>(m));
      u = u / m;
      C += __logf(m);
    }
  }

  // denominator = C + log(sum_j u[j])
  float s = u;
  s += swz<1>(s);
  s += swz<2>(s);
  s += swz<4>(s);
  s += swz<8>(s);
  float denom = C + __logf(s);

  // numerator: lanes stride over time
  float num = 0.f;
  const int* tb = targets + (size_t)b * SS;
  for (int t = j; t < SS; t += 16) {
    if (t < len) {
      int tg = tb[t];
      num += lb[t * LL + tg];
      if (t >= 1) {
        int tgp = tb[t - 1];
        num += trans[tgp * LL + tg];
      }
    }
  }
  num += swz<1>(num);
  num += swz<2>(num);
  num += swz<4>(num);
  num += swz<8>(num);

  if (j == 0) atomicAdd(out_val, denom - num);
}

extern "C" void kernel_launch(void* const* d_in, const int* in_sizes, int n_in,
                              void* d_out, int out_size, void* d_ws,
                              size_t ws_size, hipStream_t stream) {
  const float* inputs = (const float*)d_in[0];
  const int* targets = (const int*)d_in[1];
  const int* seqlen = (const int*)d_in[2];
  // d_in[3] = mask (bool) — recomputed from seqlen, unused
  const float* W = (const float*)d_in[4];
  const float* bias = (const float*)d_in[5];
  const float* trans = (const float*)d_in[6];
  float* out = (float*)d_out;

  gemm_kernel<<<1024, 256, 0, stream>>>(inputs, W, bias, out + 1);
  hipMemsetAsync(d_out, 0, sizeof(float), stream);
  crf_kernel<<<16, 64, 0, stream>>>(out + 1, targets, seqlen, trans, out);
}

// Round 2
// 97.029 us; speedup vs baseline: 2.3361x; 2.3361x over previous
//
#include <hip/hip_runtime.h>
#include <hip/hip_bf16.h>
#include <math.h>

#define BB 64
#define SS 512
#define DD 1024
#define LL 9
#define NCHUNK 32
#define CLEN 16

// ---------------- GEMM: logits[row][l] = sum_k inputs[row][k] * W[k][l] + b[l]
// (unchanged from round 1 — ~40us, optimize next round with counters)

#define DPP_ADD(v, ctrl)                                                     \
  v += __int_as_float(__builtin_amdgcn_update_dpp(                           \
      0, __float_as_int(v), ctrl, 0xF, 0xF, false))

__global__ __launch_bounds__(256) void gemm_kernel(
    const float* __restrict__ in, const float* __restrict__ W,
    const float* __restrict__ bias, float* __restrict__ out) {
  __shared__ float Wt[LL][DD];  // 36 KB
  int tid = threadIdx.x;
  for (int i = tid; i < DD * LL; i += 256) {
    int k = i / LL, l = i % LL;  // W is [k][l] row-major
    Wt[l][k] = W[i];
  }
  __syncthreads();

  int lane = tid & 63;
  int wave = tid >> 6;
  int p = lane & 15;
  int sub = lane >> 4;

  int r0 = blockIdx.x * 32 + wave * 8 + sub;  // quad 0
  int r1 = r0 + 4;                            // quad 1
  const float* x0 = in + (size_t)r0 * DD;
  const float* x1 = in + (size_t)r1 * DD;

  float acc0[LL], acc1[LL];
#pragma unroll
  for (int l = 0; l < LL; ++l) { acc0[l] = 0.f; acc1[l] = 0.f; }

  for (int it = 0; it < 16; ++it) {
    int k0 = it * 64 + p * 4;
    float4 w4[LL];
#pragma unroll
    for (int l = 0; l < LL; ++l)
      w4[l] = *reinterpret_cast<const float4*>(&Wt[l][k0]);
    float4 a = *reinterpret_cast<const float4*>(x0 + k0);
    float4 b4 = *reinterpret_cast<const float4*>(x1 + k0);
#pragma unroll
    for (int l = 0; l < LL; ++l) {
      acc0[l] += a.x * w4[l].x + a.y * w4[l].y + a.z * w4[l].z + a.w * w4[l].w;
      acc1[l] += b4.x * w4[l].x + b4.y * w4[l].y + b4.z * w4[l].z + b4.w * w4[l].w;
    }
  }

#pragma unroll
  for (int l = 0; l < LL; ++l) {
    DPP_ADD(acc0[l], 0x111);
    DPP_ADD(acc0[l], 0x112);
    DPP_ADD(acc0[l], 0x114);
    DPP_ADD(acc0[l], 0x118);
    DPP_ADD(acc1[l], 0x111);
    DPP_ADD(acc1[l], 0x112);
    DPP_ADD(acc1[l], 0x114);
    DPP_ADD(acc1[l], 0x118);
  }
  if (p == 15) {
#pragma unroll
    for (int l = 0; l < LL; ++l) {
      out[(size_t)r0 * LL + l] = acc0[l] + bias[l];
      out[(size_t)r1 * LL + l] = acc1[l] + bias[l];
    }
  }
}

template <int R>
__device__ inline float swz(float x) {
  return __int_as_float(
      __builtin_amdgcn_ds_swizzle(__float_as_int(x), (R << 10) | 0x1F));
}

// ---------------- Phase 1: per-(batch,chunk) transfer matrix.
// 16-lane group = one (b,k). Lane j holds ROW j of T (9 floats, cols 0..8).
// Step: T'[j][c] = (sum_m T[j][m]*Mexp[m][c]) * exp(e_t[c]); identity if
// t >= len (frozen alpha). Pure in-register VALU, zero cross-lane in the
// hot loop. Renorm every 8 steps (log accumulated into scale).

__global__ __launch_bounds__(64) void crf_chunk_kernel(
    const float* __restrict__ logits, const int* __restrict__ seqlen,
    const float* __restrict__ trans, float* __restrict__ mats,
    float* __restrict__ scales) {
  int lane = threadIdx.x;
  int j = lane & 15;
  int gid = blockIdx.x * 4 + (lane >> 4);
  int b = gid >> 5;   // 32 chunks per batch
  int k = gid & 31;
  int len = seqlen[b];

  float Mx[81];
#pragma unroll
  for (int i = 0; i < 81; ++i) Mx[i] = __expf(trans[i]);

  float T[LL];
#pragma unroll
  for (int c = 0; c < LL; ++c) T[c] = (j == c) ? 1.f : 0.f;  // rows 9..15 -> 0
  float Cl = 0.f;

  const float* lb = logits + (size_t)b * SS * LL;
  int t0 = k * CLEN + 1;
  int tend = (t0 + CLEN < SS) ? (t0 + CLEN) : SS;

  float e[LL];
#pragma unroll
  for (int c = 0; c < LL; ++c) e[c] = lb[t0 * LL + c];

  for (int t = t0; t < tend; ++t) {
    float Ex[LL];
#pragma unroll
    for (int c = 0; c < LL; ++c) Ex[c] = __expf(e[c]);
    if (t + 1 < tend) {
#pragma unroll
      for (int c = 0; c < LL; ++c) e[c] = lb[(t + 1) * LL + c];
    }
    bool active = (t < len);
    float nT[LL];
#pragma unroll
    for (int c = 0; c < LL; ++c) {
      float s = 0.f;
#pragma unroll
      for (int m = 0; m < LL; ++m) s += T[m] * Mx[m * LL + c];
      nT[c] = s * Ex[c];
    }
#pragma unroll
    for (int c = 0; c < LL; ++c) T[c] = active ? nT[c] : T[c];

    if (((t - t0) & 7) == 7) {
      float m = T[0];
#pragma unroll
      for (int c = 1; c < LL; ++c) m = fmaxf(m, T[c]);
      m = fmaxf(m, swz<1>(m));
      m = fmaxf(m, swz<2>(m));
      m = fmaxf(m, swz<4>(m));
      m = fmaxf(m, swz<8>(m));
      float inv = 1.f / m;
#pragma unroll
      for (int c = 0; c < LL; ++c) T[c] *= inv;
      Cl += __logf(m);
    }
  }
  // final renorm so stored matrices have max entry 1
  {
    float m = T[0];
#pragma unroll
    for (int c = 1; c < LL; ++c) m = fmaxf(m, T[c]);
    m = fmaxf(m, swz<1>(m));
    m = fmaxf(m, swz<2>(m));
    m = fmaxf(m, swz<4>(m));
    m = fmaxf(m, swz<8>(m));
    float inv = 1.f / m;
#pragma unroll
    for (int c = 0; c < LL; ++c) T[c] *= inv;
    Cl += __logf(m);
  }

  float* row = mats + ((size_t)gid * 16 + j) * 16;
#pragma unroll
  for (int c = 0; c < 16; ++c) row[c] = (c < LL) ? T[c] : 0.f;
  if (j == 0) scales[gid] = Cl;
}

// ---------------- Phase 2: per-batch combine (32 matvecs) + numerator.
// One 16-lane group per batch; lane j holds alpha[j]. XOR-swizzle matvec
// against the stored chunk matrices.

__global__ __launch_bounds__(64) void crf_combine_kernel(
    const float* __restrict__ logits, const int* __restrict__ targets,
    const int* __restrict__ seqlen, const float* __restrict__ trans,
    const float* __restrict__ mats, const float* __restrict__ scales,
    float* __restrict__ out_val) {
  int lane = threadIdx.x;
  int j = lane & 15;
  int b = blockIdx.x * 4 + (lane >> 4);
  int len = seqlen[b];
  const float* lb = logits + (size_t)b * SS * LL;

  float alpha = (j < LL) ? __expf(lb[j]) : 0.f;
  float C = 0.f;

  for (int k = 0; k < NCHUNK; ++k) {
    const float* Tm = mats + ((size_t)b * NCHUNK + k) * 256;
    float col[16];  // col[r] = T[j^r][j] — constant-indexed after unroll
#pragma unroll
    for (int r = 0; r < 16; ++r) col[r] = Tm[(j ^ r) * 16 + j];

    float v = alpha * col[0];
    v += swz<1>(alpha) * col[1];
    v += swz<2>(alpha) * col[2];
    v += swz<3>(alpha) * col[3];
    v += swz<4>(alpha) * col[4];
    v += swz<5>(alpha) * col[5];
    v += swz<6>(alpha) * col[6];
    v += swz<7>(alpha) * col[7];
    v += swz<8>(alpha) * col[8];
    v += swz<9>(alpha) * col[9];
    v += swz<10>(alpha) * col[10];
    v += swz<11>(alpha) * col[11];
    v += swz<12>(alpha) * col[12];
    v += swz<13>(alpha) * col[13];
    v += swz<14>(alpha) * col[14];
    v += swz<15>(alpha) * col[15];
    alpha = v;
    C += scales[b * NCHUNK + k];

    float m = alpha;
    m = fmaxf(m, swz<1>(m));
    m = fmaxf(m, swz<2>(m));
    m = fmaxf(m, swz<4>(m));
    m = fmaxf(m, swz<8>(m));
    float inv = 1.f / m;
    alpha *= inv;
    C += __logf(m);
  }

  float s = alpha;
  s += swz<1>(s);
  s += swz<2>(s);
  s += swz<4>(s);
  s += swz<8>(s);
  float denom = C + __logf(s);

  // numerator: lanes stride over time
  float num = 0.f;
  const int* tb = targets + (size_t)b * SS;
  for (int t = j; t < SS; t += 16) {
    if (t < len) {
      int tg = tb[t];
      num += lb[t * LL + tg];
      if (t >= 1) {
        int tgp = tb[t - 1];
        num += trans[tgp * LL + tg];
      }
    }
  }
  num += swz<1>(num);
  num += swz<2>(num);
  num += swz<4>(num);
  num += swz<8>(num);

  if (j == 0) atomicAdd(out_val, denom - num);
}

extern "C" void kernel_launch(void* const* d_in, const int* in_sizes, int n_in,
                              void* d_out, int out_size, void* d_ws,
                              size_t ws_size, hipStream_t stream) {
  const float* inputs = (const float*)d_in[0];
  const int* targets = (const int*)d_in[1];
  const int* seqlen = (const int*)d_in[2];
  // d_in[3] = mask (bool) — recomputed from seqlen, unused
  const float* W = (const float*)d_in[4];
  const float* bias = (const float*)d_in[5];
  const float* trans = (const float*)d_in[6];
  float* out = (float*)d_out;

  float* mats = (float*)d_ws;                       // 64*32*256 floats = 2 MB
  float* scales = mats + (size_t)BB * NCHUNK * 256; // 2048 floats

  gemm_kernel<<<1024, 256, 0, stream>>>(inputs, W, bias, out + 1);
  crf_chunk_kernel<<<BB * NCHUNK / 4, 64, 0, stream>>>(out + 1, seqlen, trans,
                                                       mats, scales);
  hipMemsetAsync(d_out, 0, sizeof(float), stream);
  crf_combine_kernel<<<BB / 4, 64, 0, stream>>>(out + 1, targets, seqlen,
                                                trans, mats, scales, out);
}

// Round 3
// 56.190 us; speedup vs baseline: 4.0339x; 1.7268x over previous
//
#include <hip/hip_runtime.h>
#include <hip/hip_bf16.h>
#include <math.h>

#define BB 64
#define SS 512
#define DD 1024
#define LL 9
#define NCHUNK 32
#define CLEN 16

#define DPP_ADD(v, ctrl)                                                     \
  v += __int_as_float(__builtin_amdgcn_update_dpp(                           \
      0, __float_as_int(v), ctrl, 0xF, 0xF, false))

// ---------------- GEMM: logits[row][l] = sum_k in[row][k]*W[k][l] + b[l]
// 512 blocks x 256 threads; block = 64 rows; wave = 16 rows (4 subs x 4 q).
// 16-lane K-split (p); w4[9] LDS read reused across 4 rows -> LDS
// amplification 2.25x (was 4.5x), off the critical path. DPP row_shr reduce.
__global__ __launch_bounds__(256) void gemm_kernel(
    const float* __restrict__ in, const float* __restrict__ W,
    const float* __restrict__ bias, float* __restrict__ out) {
  __shared__ float Wt[LL][DD];  // 36 KB
  int tid = threadIdx.x;
  for (int i = tid; i < DD * LL; i += 256) {
    int k = i / LL, l = i % LL;  // W row-major [k][l]
    Wt[l][k] = W[i];
  }
  __syncthreads();

  int lane = tid & 63;
  int wave = tid >> 6;
  int p = lane & 15;
  int sub = lane >> 4;

  int r0 = blockIdx.x * 64 + wave * 16 + sub;  // rows r0 + 4q, q=0..3
  const float* x0 = in + (size_t)r0 * DD;

  float acc[4][LL];
#pragma unroll
  for (int q = 0; q < 4; ++q)
#pragma unroll
    for (int l = 0; l < LL; ++l) acc[q][l] = 0.f;

  for (int it = 0; it < 16; ++it) {
    int k0 = it * 64 + p * 4;
    float4 w4[LL];
#pragma unroll
    for (int l = 0; l < LL; ++l)
      w4[l] = *reinterpret_cast<const float4*>(&Wt[l][k0]);
    float4 a[4];
#pragma unroll
    for (int q = 0; q < 4; ++q)
      a[q] = *reinterpret_cast<const float4*>(x0 + (size_t)q * 4 * DD + k0);
#pragma unroll
    for (int q = 0; q < 4; ++q)
#pragma unroll
      for (int l = 0; l < LL; ++l)
        acc[q][l] += a[q].x * w4[l].x + a[q].y * w4[l].y + a[q].z * w4[l].z +
                     a[q].w * w4[l].w;
  }

#pragma unroll
  for (int q = 0; q < 4; ++q)
#pragma unroll
    for (int l = 0; l < LL; ++l) {
      DPP_ADD(acc[q][l], 0x111);
      DPP_ADD(acc[q][l], 0x112);
      DPP_ADD(acc[q][l], 0x114);
      DPP_ADD(acc[q][l], 0x118);
    }
  if (p == 15) {
#pragma unroll
    for (int q = 0; q < 4; ++q)
#pragma unroll
      for (int l = 0; l < LL; ++l)
        out[(size_t)(r0 + q * 4) * LL + l] = acc[q][l] + bias[l];
  }
}

template <int R>
__device__ inline float swz(float x) {
  return __int_as_float(
      __builtin_amdgcn_ds_swizzle(__float_as_int(x), (R << 10) | 0x1F));
}

// ---------------- Phase 1: per-(batch,chunk) 16-step transfer matrix.
// Lane j holds ROW j of T. Pure in-register VALU hot loop. Stores mats
// PRE-PERMUTED for combine: value T[i][c] -> offset c*16 + (i^c), so
// combine lane j reads col[r]=T[j^r][j] as 4 contiguous float4s.
__global__ __launch_bounds__(64) void crf_chunk_kernel(
    const float* __restrict__ logits, const int* __restrict__ seqlen,
    const float* __restrict__ trans, float* __restrict__ mats,
    float* __restrict__ scales) {
  int lane = threadIdx.x;
  int j = lane & 15;
  int gid = blockIdx.x * 4 + (lane >> 4);
  int b = gid >> 5;
  int k = gid & 31;
  int len = seqlen[b];

  float Mx[81];
#pragma unroll
  for (int i = 0; i < 81; ++i) Mx[i] = __expf(trans[i]);

  float T[LL];
#pragma unroll
  for (int c = 0; c < LL; ++c) T[c] = (j == c) ? 1.f : 0.f;
  float Cl = 0.f;

  const float* lb = logits + (size_t)b * SS * LL;
  int t0 = k * CLEN + 1;
  int tend = (t0 + CLEN < SS) ? (t0 + CLEN) : SS;

  float e[LL];
#pragma unroll
  for (int c = 0; c < LL; ++c) e[c] = lb[t0 * LL + c];

  for (int t = t0; t < tend; ++t) {
    float Ex[LL];
#pragma unroll
    for (int c = 0; c < LL; ++c) Ex[c] = __expf(e[c]);
    if (t + 1 < tend) {
#pragma unroll
      for (int c = 0; c < LL; ++c) e[c] = lb[(t + 1) * LL + c];
    }
    bool active = (t < len);
    float nT[LL];
#pragma unroll
    for (int c = 0; c < LL; ++c) {
      float s = 0.f;
#pragma unroll
      for (int m = 0; m < LL; ++m) s += T[m] * Mx[m * LL + c];
      nT[c] = s * Ex[c];
    }
#pragma unroll
    for (int c = 0; c < LL; ++c) T[c] = active ? nT[c] : T[c];

    if (((t - t0) & 7) == 7) {
      float m = T[0];
#pragma unroll
      for (int c = 1; c < LL; ++c) m = fmaxf(m, T[c]);
      m = fmaxf(m, swz<1>(m));
      m = fmaxf(m, swz<2>(m));
      m = fmaxf(m, swz<4>(m));
      m = fmaxf(m, swz<8>(m));
      float inv = 1.f / m;
#pragma unroll
      for (int c = 0; c < LL; ++c) T[c] *= inv;
      Cl += __logf(m);
    }
  }
  {
    float m = T[0];
#pragma unroll
    for (int c = 1; c < LL; ++c) m = fmaxf(m, T[c]);
    m = fmaxf(m, swz<1>(m));
    m = fmaxf(m, swz<2>(m));
    m = fmaxf(m, swz<4>(m));
    m = fmaxf(m, swz<8>(m));
    float inv = 1.f / m;
#pragma unroll
    for (int c = 0; c < LL; ++c) T[c] *= inv;
    Cl += __logf(m);
  }

  float* Mg = mats + (size_t)gid * 256;
#pragma unroll
  for (int c = 0; c < 16; ++c)
    Mg[c * 16 + (j ^ c)] = (c < LL) ? T[c] : 0.f;
  if (j == 0) scales[gid] = Cl;
}

// ---------------- Phase 2: per-batch combine + numerator.
// One wave per batch. Matvec in 16-lane groups (redundant across groups);
// chunk-matrix columns double-buffered one chunk ahead (4x float4 reads).
// Numerator gathered across all 64 lanes.
__global__ __launch_bounds__(64) void crf_combine_kernel(
    const float* __restrict__ logits, const int* __restrict__ targets,
    const int* __restrict__ seqlen, const float* __restrict__ trans,
    const float* __restrict__ mats, const float* __restrict__ scales,
    float* __restrict__ out_val) {
  int lane = threadIdx.x;
  int j = lane & 15;
  int b = blockIdx.x;
  int len = seqlen[b];
  const float* lb = logits + (size_t)b * SS * LL;
  const float* Mb = mats + (size_t)b * NCHUNK * 256;
  const float* Sb = scales + (size_t)b * NCHUNK;

  float alpha = (j < LL) ? __expf(lb[j]) : 0.f;
  float C = 0.f;

  float4 c0 = *reinterpret_cast<const float4*>(Mb + j * 16 + 0);
  float4 c1 = *reinterpret_cast<const float4*>(Mb + j * 16 + 4);
  float4 c2 = *reinterpret_cast<const float4*>(Mb + j * 16 + 8);
  float4 c3 = *reinterpret_cast<const float4*>(Mb + j * 16 + 12);

  for (int k = 0; k < NCHUNK; ++k) {
    float4 n0, n1, n2, n3;
    if (k + 1 < NCHUNK) {
      const float* Mn = Mb + (size_t)(k + 1) * 256 + j * 16;
      n0 = *reinterpret_cast<const float4*>(Mn + 0);
      n1 = *reinterpret_cast<const float4*>(Mn + 4);
      n2 = *reinterpret_cast<const float4*>(Mn + 8);
      n3 = *reinterpret_cast<const float4*>(Mn + 12);
    }
    float v = alpha * c0.x;
    v += swz<1>(alpha) * c0.y;
    v += swz<2>(alpha) * c0.z;
    v += swz<3>(alpha) * c0.w;
    v += swz<4>(alpha) * c1.x;
    v += swz<5>(alpha) * c1.y;
    v += swz<6>(alpha) * c1.z;
    v += swz<7>(alpha) * c1.w;
    v += swz<8>(alpha) * c2.x;
    v += swz<9>(alpha) * c2.y;
    v += swz<10>(alpha) * c2.z;
    v += swz<11>(alpha) * c2.w;
    v += swz<12>(alpha) * c3.x;
    v += swz<13>(alpha) * c3.y;
    v += swz<14>(alpha) * c3.z;
    v += swz<15>(alpha) * c3.w;
    alpha = v;
    C += Sb[k];

    float m = alpha;
    m = fmaxf(m, swz<1>(m));
    m = fmaxf(m, swz<2>(m));
    m = fmaxf(m, swz<4>(m));
    m = fmaxf(m, swz<8>(m));
    float inv = 1.f / m;
    alpha *= inv;
    C += __logf(m);

    if (k + 1 < NCHUNK) { c0 = n0; c1 = n1; c2 = n2; c3 = n3; }
  }

  float s = alpha;
  s += swz<1>(s);
  s += swz<2>(s);
  s += swz<4>(s);
  s += swz<8>(s);
  float denom = C + __logf(s);

  // numerator over all 64 lanes
  float num = 0.f;
  const int* tb = targets + (size_t)b * SS;
  for (int t = lane; t < SS; t += 64) {
    if (t < len) {
      int tg = tb[t];
      num += lb[t * LL + tg];
      if (t >= 1) {
        int tgp = tb[t - 1];
        num += trans[tgp * LL + tg];
      }
    }
  }
  num += __shfl_xor(num, 1, 64);
  num += __shfl_xor(num, 2, 64);
  num += __shfl_xor(num, 4, 64);
  num += __shfl_xor(num, 8, 64);
  num += __shfl_xor(num, 16, 64);
  num += __shfl_xor(num, 32, 64);

  if (lane == 0) atomicAdd(out_val, denom - num);
}

extern "C" void kernel_launch(void* const* d_in, const int* in_sizes, int n_in,
                              void* d_out, int out_size, void* d_ws,
                              size_t ws_size, hipStream_t stream) {
  const float* inputs = (const float*)d_in[0];
  const int* targets = (const int*)d_in[1];
  const int* seqlen = (const int*)d_in[2];
  const float* W = (const float*)d_in[4];
  const float* bias = (const float*)d_in[5];
  const float* trans = (const float*)d_in[6];
  float* out = (float*)d_out;

  float* mats = (float*)d_ws;                        // 64*32*256 f = 2 MB
  float* scales = mats + (size_t)BB * NCHUNK * 256;  // 2048 floats

  gemm_kernel<<<512, 256, 0, stream>>>(inputs, W, bias, out + 1);
  crf_chunk_kernel<<<BB * NCHUNK / 4, 64, 0, stream>>>(out + 1, seqlen, trans,
                                                       mats, scales);
  hipMemsetAsync(d_out, 0, sizeof(float), stream);
  crf_combine_kernel<<<BB, 64, 0, stream>>>(out + 1, targets, seqlen, trans,
                                            mats, scales, out);
}

// Round 4
// 53.523 us; speedup vs baseline: 4.2350x; 1.0498x over previous
//
#include <hip/hip_runtime.h>
#include <hip/hip_bf16.h>
#include <math.h>

#define BB 64
#define SS 512
#define DD 1024
#define LL 9
#define NCHUNK 32
#define CLEN 16

#define DPP_ADD(v, ctrl)                                                     \
  v += __int_as_float(__builtin_amdgcn_update_dpp(                           \
      0, __float_as_int(v), ctrl, 0xF, 0xF, false))

// ---------------- GEMM: logits[row][l] = sum_k in[row][k]*W[k][l] + b[l]
// 512 blocks x 256 threads; wave = 16 rows (4 subs x 4 q). 16-lane K-split.
// Global a[] loads software-pipelined 1 iteration ahead so each wave always
// has 4 float4 loads in flight during the 288-cycle FMA block.
__global__ __launch_bounds__(256) void gemm_kernel(
    const float* __restrict__ in, const float* __restrict__ W,
    const float* __restrict__ bias, float* __restrict__ out) {
  __shared__ float Wt[LL][DD];  // 36 KB
  int tid = threadIdx.x;
  for (int i = tid; i < DD * LL; i += 256) {
    int k = i / LL, l = i - k * LL;  // W row-major [k][l]
    Wt[l][k] = W[i];
  }
  __syncthreads();

  int lane = tid & 63;
  int wave = tid >> 6;
  int p = lane & 15;
  int sub = lane >> 4;

  int r0 = blockIdx.x * 64 + wave * 16 + sub;  // rows r0 + 4q, q=0..3
  const float* x0 = in + (size_t)r0 * DD + p * 4;

  float acc[4][LL];
#pragma unroll
  for (int q = 0; q < 4; ++q)
#pragma unroll
    for (int l = 0; l < LL; ++l) acc[q][l] = 0.f;

  float4 a[4], an[4];
#pragma unroll
  for (int q = 0; q < 4; ++q)
    a[q] = *reinterpret_cast<const float4*>(x0 + (size_t)q * 4 * DD);

  for (int it = 0; it < 16; ++it) {
    if (it < 15) {
#pragma unroll
      for (int q = 0; q < 4; ++q)
        an[q] = *reinterpret_cast<const float4*>(x0 + (size_t)q * 4 * DD +
                                                 (it + 1) * 64);
    }
    int k0 = it * 64 + p * 4;
    float4 w4[LL];
#pragma unroll
    for (int l = 0; l < LL; ++l)
      w4[l] = *reinterpret_cast<const float4*>(&Wt[l][k0]);
#pragma unroll
    for (int q = 0; q < 4; ++q)
#pragma unroll
      for (int l = 0; l < LL; ++l)
        acc[q][l] += a[q].x * w4[l].x + a[q].y * w4[l].y + a[q].z * w4[l].z +
                     a[q].w * w4[l].w;
    if (it < 15) {
#pragma unroll
      for (int q = 0; q < 4; ++q) a[q] = an[q];
    }
  }

#pragma unroll
  for (int q = 0; q < 4; ++q)
#pragma unroll
    for (int l = 0; l < LL; ++l) {
      DPP_ADD(acc[q][l], 0x111);
      DPP_ADD(acc[q][l], 0x112);
      DPP_ADD(acc[q][l], 0x114);
      DPP_ADD(acc[q][l], 0x118);
    }
  if (p == 15) {
#pragma unroll
    for (int q = 0; q < 4; ++q)
#pragma unroll
      for (int l = 0; l < LL; ++l)
        out[(size_t)(r0 + q * 4) * LL + l] = acc[q][l] + bias[l];
  }
}

template <int R>
__device__ inline float swz(float x) {
  return __int_as_float(
      __builtin_amdgcn_ds_swizzle(__float_as_int(x), (R << 10) | 0x1F));
}

// ---------------- Phase 1: per-(batch,chunk) 16-step transfer matrix +
// per-chunk numerator partial. Lane j holds ROW j of T. Mats stored
// pre-permuted: T[i][c] -> offset c*16 + (i^c). Block 0 also zeroes the
// finisher counter for this call (combine runs after, stream-ordered).
__global__ __launch_bounds__(64) void crf_chunk_kernel(
    const float* __restrict__ logits, const int* __restrict__ targets,
    const int* __restrict__ seqlen, const float* __restrict__ trans,
    float* __restrict__ mats, float* __restrict__ scales,
    float* __restrict__ numpart, unsigned* __restrict__ counter) {
  if (blockIdx.x == 0 && threadIdx.x == 0) *counter = 0u;

  int lane = threadIdx.x;
  int j = lane & 15;
  int gid = blockIdx.x * 4 + (lane >> 4);
  int b = gid >> 5;
  int k = gid & 31;
  int len = seqlen[b];

  float Mx[81];
#pragma unroll
  for (int i = 0; i < 81; ++i) Mx[i] = __expf(trans[i]);

  float T[LL];
#pragma unroll
  for (int c = 0; c < LL; ++c) T[c] = (j == c) ? 1.f : 0.f;
  float Cl = 0.f;

  const float* lb = logits + (size_t)b * SS * LL;
  const int* tb = targets + (size_t)b * SS;
  int t0 = k * CLEN + 1;
  int tend = (t0 + CLEN < SS) ? (t0 + CLEN) : SS;

  float e[LL];
#pragma unroll
  for (int c = 0; c < LL; ++c) e[c] = lb[t0 * LL + c];

  for (int t = t0; t < tend; ++t) {
    float Ex[LL];
#pragma unroll
    for (int c = 0; c < LL; ++c) Ex[c] = __expf(e[c]);
    if (t + 1 < tend) {
#pragma unroll
      for (int c = 0; c < LL; ++c) e[c] = lb[(t + 1) * LL + c];
    }
    bool active = (t < len);
    float nT[LL];
#pragma unroll
    for (int c = 0; c < LL; ++c) {
      float s = 0.f;
#pragma unroll
      for (int m = 0; m < LL; ++m) s += T[m] * Mx[m * LL + c];
      nT[c] = s * Ex[c];
    }
#pragma unroll
    for (int c = 0; c < LL; ++c) T[c] = active ? nT[c] : T[c];

    if (((t - t0) & 7) == 7) {
      float m = T[0];
#pragma unroll
      for (int c = 1; c < LL; ++c) m = fmaxf(m, T[c]);
      m = fmaxf(m, swz<1>(m));
      m = fmaxf(m, swz<2>(m));
      m = fmaxf(m, swz<4>(m));
      m = fmaxf(m, swz<8>(m));
      float inv = 1.f / m;
#pragma unroll
      for (int c = 0; c < LL; ++c) T[c] *= inv;
      Cl += __logf(m);
    }
  }
  {
    float m = T[0];
#pragma unroll
    for (int c = 1; c < LL; ++c) m = fmaxf(m, T[c]);
    m = fmaxf(m, swz<1>(m));
    m = fmaxf(m, swz<2>(m));
    m = fmaxf(m, swz<4>(m));
    m = fmaxf(m, swz<8>(m));
    float inv = 1.f / m;
#pragma unroll
    for (int c = 0; c < LL; ++c) T[c] *= inv;
    Cl += __logf(m);
  }

  float* Mg = mats + (size_t)gid * 256;
#pragma unroll
  for (int c = 0; c < 16; ++c)
    Mg[c * 16 + (j ^ c)] = (c < LL) ? T[c] : 0.f;
  if (j == 0) scales[gid] = Cl;

  // numerator partial for t in [t0, tend): lane j handles t = t0 + j
  int t = t0 + j;
  float np = 0.f;
  if (t < tend && t < len) {
    int tg = tb[t];
    np = lb[t * LL + tg] + trans[tb[t - 1] * LL + tg];
  }
  np += swz<1>(np);
  np += swz<2>(np);
  np += swz<4>(np);
  np += swz<8>(np);
  if (j == 0) numpart[gid] = np;
}

// ---------------- Phase 2: per-batch combine (matvec tree, renorm every 4
// chunks) + deterministic final reduce via last-block finisher.
__global__ __launch_bounds__(64) void crf_combine_kernel(
    const float* __restrict__ logits, const int* __restrict__ targets,
    const float* __restrict__ mats, const float* __restrict__ scales,
    const float* __restrict__ numpart, float* __restrict__ partials,
    unsigned* __restrict__ counter, float* __restrict__ out_val) {
  int lane = threadIdx.x;
  int j = lane & 15;
  int b = blockIdx.x;
  const float* lb = logits + (size_t)b * SS * LL;
  const float* Mb = mats + (size_t)b * NCHUNK * 256;

  // parallel: sum of chunk scales minus numerator partials (fixed order)
  float extra = (lane < NCHUNK) ? scales[b * NCHUNK + lane]
                                : -numpart[b * NCHUNK + (lane - 32)];
  extra += __shfl_xor(extra, 1, 64);
  extra += __shfl_xor(extra, 2, 64);
  extra += __shfl_xor(extra, 4, 64);
  extra += __shfl_xor(extra, 8, 64);
  extra += __shfl_xor(extra, 16, 64);
  extra += __shfl_xor(extra, 32, 64);
  float emit0 = lb[targets[(size_t)b * SS]];  // t=0 numerator term

  float alpha = (j < LL) ? __expf(lb[j]) : 0.f;
  float C = 0.f;

  float4 c0 = *reinterpret_cast<const float4*>(Mb + j * 16 + 0);
  float4 c1 = *reinterpret_cast<const float4*>(Mb + j * 16 + 4);
  float4 c2 = *reinterpret_cast<const float4*>(Mb + j * 16 + 8);
  float4 c3 = *reinterpret_cast<const float4*>(Mb + j * 16 + 12);

  for (int k = 0; k < NCHUNK; ++k) {
    float4 n0, n1, n2, n3;
    if (k + 1 < NCHUNK) {
      const float* Mn = Mb + (size_t)(k + 1) * 256 + j * 16;
      n0 = *reinterpret_cast<const float4*>(Mn + 0);
      n1 = *reinterpret_cast<const float4*>(Mn + 4);
      n2 = *reinterpret_cast<const float4*>(Mn + 8);
      n3 = *reinterpret_cast<const float4*>(Mn + 12);
    }
    float s01 = alpha * c0.x + swz<1>(alpha) * c0.y;
    float s23 = swz<2>(alpha) * c0.z + swz<3>(alpha) * c0.w;
    float s45 = swz<4>(alpha) * c1.x + swz<5>(alpha) * c1.y;
    float s67 = swz<6>(alpha) * c1.z + swz<7>(alpha) * c1.w;
    float s89 = swz<8>(alpha) * c2.x + swz<9>(alpha) * c2.y;
    float sab = swz<10>(alpha) * c2.z + swz<11>(alpha) * c2.w;
    float scd = swz<12>(alpha) * c3.x + swz<13>(alpha) * c3.y;
    float sef = swz<14>(alpha) * c3.z + swz<15>(alpha) * c3.w;
    alpha = ((s01 + s23) + (s45 + s67)) + ((s89 + sab) + (scd + sef));

    if ((k & 3) == 3) {  // renorm every 4 chunks (growth <= 9^4, safe)
      float m = alpha;
      m = fmaxf(m, swz<1>(m));
      m = fmaxf(m, swz<2>(m));
      m = fmaxf(m, swz<4>(m));
      m = fmaxf(m, swz<8>(m));
      float inv = 1.f / m;
      alpha *= inv;
      C += __logf(m);
    }
    if (k + 1 < NCHUNK) { c0 = n0; c1 = n1; c2 = n2; c3 = n3; }
  }

  float s = alpha;
  s += swz<1>(s);
  s += swz<2>(s);
  s += swz<4>(s);
  s += swz<8>(s);
  float result = extra + C + __logf(s) - emit0;

  if (lane == 0) partials[b] = result;
  __threadfence();
  unsigned old = 0;
  if (lane == 0) old = atomicAdd(counter, 1u);
  old = __shfl(old, 0, 64);
  if (old == BB - 1) {  // last block: deterministic fixed-order reduce
    __threadfence();
    float v = partials[lane];
    v += __shfl_xor(v, 1, 64);
    v += __shfl_xor(v, 2, 64);
    v += __shfl_xor(v, 4, 64);
    v += __shfl_xor(v, 8, 64);
    v += __shfl_xor(v, 16, 64);
    v += __shfl_xor(v, 32, 64);
    if (lane == 0) {
      out_val[0] = v;
      *counter = 0u;
    }
  }
}

extern "C" void kernel_launch(void* const* d_in, const int* in_sizes, int n_in,
                              void* d_out, int out_size, void* d_ws,
                              size_t ws_size, hipStream_t stream) {
  const float* inputs = (const float*)d_in[0];
  const int* targets = (const int*)d_in[1];
  const int* seqlen = (const int*)d_in[2];
  const float* W = (const float*)d_in[4];
  const float* bias = (const float*)d_in[5];
  const float* trans = (const float*)d_in[6];
  float* out = (float*)d_out;

  float* mats = (float*)d_ws;                        // 64*32*256 f = 2 MB
  float* scales = mats + (size_t)BB * NCHUNK * 256;  // 2048 f
  float* numpart = scales + (size_t)BB * NCHUNK;     // 2048 f
  float* partials = numpart + (size_t)BB * NCHUNK;   // 64 f
  unsigned* counter = (unsigned*)(partials + BB);    // 1 u32

  gemm_kernel<<<512, 256, 0, stream>>>(inputs, W, bias, out + 1);
  crf_chunk_kernel<<<BB * NCHUNK / 4, 64, 0, stream>>>(
      out + 1, targets, seqlen, trans, mats, scales, numpart, counter);
  crf_combine_kernel<<<BB, 64, 0, stream>>>(out + 1, targets, mats, scales,
                                            numpart, partials, counter, out);
}

// Round 5
// 52.965 us; speedup vs baseline: 4.2796x; 1.0105x over previous
//
#include <hip/hip_runtime.h>
#include <hip/hip_bf16.h>
#include <math.h>

#define BB 64
#define SS 512
#define DD 1024
#define LL 9
#define NCHUNK 32

#define DPP_ADD(v, ctrl)                                                     \
  v += __int_as_float(__builtin_amdgcn_update_dpp(                           \
      0, __float_as_int(v), ctrl, 0xF, 0xF, false))

template <int R>
__device__ inline float swz(float x) {
  return __int_as_float(
      __builtin_amdgcn_ds_swizzle(__float_as_int(x), (R << 10) | 0x1F));
}

// ---------------- Fused GEMM + chunk-scan kernel.
// 512 blocks x 256 threads; block = 64 rows = 4 chunks of one batch.
// Phase 1 (all 4 waves): logits GEMM, results -> global AND LDS.
// Phase 2: wave 0 runs 4 transfer-matrix chunks (16-lane groups, emissions
// from LDS); wave 1 computes the block's 64 numerator terms.
// Chunk partition: chunk 0 = steps 1..15; chunk k = steps 16k..16k+15,
// so every chunk's emission rows live inside its own block.
__global__ __launch_bounds__(256) void fused_kernel(
    const float* __restrict__ in, const float* __restrict__ W,
    const float* __restrict__ bias, const int* __restrict__ targets,
    const int* __restrict__ seqlen, const float* __restrict__ trans,
    float* __restrict__ logits, float* __restrict__ mats,
    float* __restrict__ scales, float* __restrict__ numblk,
    unsigned* __restrict__ counter) {
  __shared__ float Wt[LL][DD];  // 36 KB
  __shared__ float Lg[64][LL];  // 2.25 KB: this block's logits rows
  int tid = threadIdx.x;
  int bid = blockIdx.x;
  if (bid == 0 && tid == 0) *counter = 0u;  // for combine's finisher

  for (int i = tid; i < DD * LL; i += 256) {
    int k = i / LL, l = i - k * LL;  // W row-major [k][l]
    Wt[l][k] = W[i];
  }
  __syncthreads();

  int lane = tid & 63;
  int wave = tid >> 6;
  int p = lane & 15;
  int sub = lane >> 4;

  int r0 = bid * 64 + wave * 16 + sub;  // rows r0 + 4q, q=0..3
  const float* x0 = in + (size_t)r0 * DD + p * 4;

  float acc[4][LL];
#pragma unroll
  for (int q = 0; q < 4; ++q)
#pragma unroll
    for (int l = 0; l < LL; ++l) acc[q][l] = 0.f;

  float4 a[4], an[4];
#pragma unroll
  for (int q = 0; q < 4; ++q)
    a[q] = *reinterpret_cast<const float4*>(x0 + (size_t)q * 4 * DD);

  for (int it = 0; it < 16; ++it) {
    if (it < 15) {
#pragma unroll
      for (int q = 0; q < 4; ++q)
        an[q] = *reinterpret_cast<const float4*>(x0 + (size_t)q * 4 * DD +
                                                 (it + 1) * 64);
    }
    int k0 = it * 64 + p * 4;
    float4 w4[LL];
#pragma unroll
    for (int l = 0; l < LL; ++l)
      w4[l] = *reinterpret_cast<const float4*>(&Wt[l][k0]);
#pragma unroll
    for (int q = 0; q < 4; ++q)
#pragma unroll
      for (int l = 0; l < LL; ++l)
        acc[q][l] += a[q].x * w4[l].x + a[q].y * w4[l].y + a[q].z * w4[l].z +
                     a[q].w * w4[l].w;
    if (it < 15) {
#pragma unroll
      for (int q = 0; q < 4; ++q) a[q] = an[q];
    }
  }

#pragma unroll
  for (int q = 0; q < 4; ++q)
#pragma unroll
    for (int l = 0; l < LL; ++l) {
      DPP_ADD(acc[q][l], 0x111);
      DPP_ADD(acc[q][l], 0x112);
      DPP_ADD(acc[q][l], 0x114);
      DPP_ADD(acc[q][l], 0x118);
    }
  if (p == 15) {
#pragma unroll
    for (int q = 0; q < 4; ++q)
#pragma unroll
      for (int l = 0; l < LL; ++l) {
        float v = acc[q][l] + bias[l];
        logits[(size_t)(r0 + q * 4) * LL + l] = v;
        Lg[wave * 16 + sub + q * 4][l] = v;
      }
  }
  __syncthreads();

  int b = bid >> 3;
  int base = (bid & 7) * 64;  // block's first in-batch timestep
  int len = seqlen[b];

  if (wave == 0) {
    // ---- 4 transfer-matrix chunks, data-parallel across 16-lane groups
    int j = lane & 15;
    int g = lane >> 4;
    int kk = (bid & 7) * 4 + g;  // chunk index in batch, 0..31
    int gid = b * NCHUNK + kk;

    float Mx[81];
#pragma unroll
    for (int i = 0; i < 81; ++i) Mx[i] = __expf(trans[i]);

    float T[LL];
#pragma unroll
    for (int c = 0; c < LL; ++c) T[c] = (j == c) ? 1.f : 0.f;
    float Cl = 0.f;

    int tstart = (kk == 0) ? 1 : kk * 16;
    int tend = kk * 16 + 16;

    float e[LL];
#pragma unroll
    for (int c = 0; c < LL; ++c) e[c] = Lg[tstart - base][c];

    for (int t = tstart; t < tend; ++t) {
      float Ex[LL];
#pragma unroll
      for (int c = 0; c < LL; ++c) Ex[c] = __expf(e[c]);
      if (t + 1 < tend) {
#pragma unroll
        for (int c = 0; c < LL; ++c) e[c] = Lg[t + 1 - base][c];
      }
      bool active = (t < len);
      float nT[LL];
#pragma unroll
      for (int c = 0; c < LL; ++c) {
        float s = 0.f;
#pragma unroll
        for (int m = 0; m < LL; ++m) s += T[m] * Mx[m * LL + c];
        nT[c] = s * Ex[c];
      }
#pragma unroll
      for (int c = 0; c < LL; ++c) T[c] = active ? nT[c] : T[c];

      if (((t - tstart) & 7) == 7) {
        float m = T[0];
#pragma unroll
        for (int c = 1; c < LL; ++c) m = fmaxf(m, T[c]);
        m = fmaxf(m, swz<1>(m));
        m = fmaxf(m, swz<2>(m));
        m = fmaxf(m, swz<4>(m));
        m = fmaxf(m, swz<8>(m));
        float inv = 1.f / m;
#pragma unroll
        for (int c = 0; c < LL; ++c) T[c] *= inv;
        Cl += __logf(m);
      }
    }
    {
      float m = T[0];
#pragma unroll
      for (int c = 1; c < LL; ++c) m = fmaxf(m, T[c]);
      m = fmaxf(m, swz<1>(m));
      m = fmaxf(m, swz<2>(m));
      m = fmaxf(m, swz<4>(m));
      m = fmaxf(m, swz<8>(m));
      float inv = 1.f / m;
#pragma unroll
      for (int c = 0; c < LL; ++c) T[c] *= inv;
      Cl += __logf(m);
    }

    float* Mg = mats + (size_t)gid * 256;
#pragma unroll
    for (int c = 0; c < 16; ++c)
      Mg[c * 16 + (j ^ c)] = (c < LL) ? T[c] : 0.f;
    if (j == 0) scales[gid] = Cl;
  } else if (wave == 1) {
    // ---- numerator partial for this block's 64 timesteps
    int t = base + lane;
    float np = 0.f;
    const int* tb = targets + (size_t)b * SS;
    if (t >= 1 && t < len) {
      int tg = tb[t];
      np = Lg[lane][tg] + trans[tb[t - 1] * LL + tg];
    }
    np += __shfl_xor(np, 1, 64);
    np += __shfl_xor(np, 2, 64);
    np += __shfl_xor(np, 4, 64);
    np += __shfl_xor(np, 8, 64);
    np += __shfl_xor(np, 16, 64);
    np += __shfl_xor(np, 32, 64);
    if (lane == 0) numblk[bid] = np;
  }
}

// ---------------- Combine: per-batch matvec chain over 32 chunk matrices
// (tree-associated, renorm every 4 chunks) + deterministic final reduce.
__global__ __launch_bounds__(64) void crf_combine_kernel(
    const float* __restrict__ logits, const int* __restrict__ targets,
    const float* __restrict__ mats, const float* __restrict__ scales,
    const float* __restrict__ numblk, float* __restrict__ partials,
    unsigned* __restrict__ counter, float* __restrict__ out_val) {
  int lane = threadIdx.x;
  int j = lane & 15;
  int b = blockIdx.x;
  const float* lb = logits + (size_t)b * SS * LL;
  const float* Mb = mats + (size_t)b * NCHUNK * 256;

  // scales (32 lanes) minus numerator block partials (8 lanes), fixed order
  float extra = 0.f;
  if (lane < NCHUNK) extra = scales[b * NCHUNK + lane];
  else if (lane < NCHUNK + 8) extra = -numblk[b * 8 + (lane - NCHUNK)];
  extra += __shfl_xor(extra, 1, 64);
  extra += __shfl_xor(extra, 2, 64);
  extra += __shfl_xor(extra, 4, 64);
  extra += __shfl_xor(extra, 8, 64);
  extra += __shfl_xor(extra, 16, 64);
  extra += __shfl_xor(extra, 32, 64);
  float emit0 = lb[targets[(size_t)b * SS]];  // t=0 numerator term

  float alpha = (j < LL) ? __expf(lb[j]) : 0.f;
  float C = 0.f;

  float4 c0 = *reinterpret_cast<const float4*>(Mb + j * 16 + 0);
  float4 c1 = *reinterpret_cast<const float4*>(Mb + j * 16 + 4);
  float4 c2 = *reinterpret_cast<const float4*>(Mb + j * 16 + 8);
  float4 c3 = *reinterpret_cast<const float4*>(Mb + j * 16 + 12);

  for (int k = 0; k < NCHUNK; ++k) {
    float4 n0, n1, n2, n3;
    if (k + 1 < NCHUNK) {
      const float* Mn = Mb + (size_t)(k + 1) * 256 + j * 16;
      n0 = *reinterpret_cast<const float4*>(Mn + 0);
      n1 = *reinterpret_cast<const float4*>(Mn + 4);
      n2 = *reinterpret_cast<const float4*>(Mn + 8);
      n3 = *reinterpret_cast<const float4*>(Mn + 12);
    }
    float s01 = alpha * c0.x + swz<1>(alpha) * c0.y;
    float s23 = swz<2>(alpha) * c0.z + swz<3>(alpha) * c0.w;
    float s45 = swz<4>(alpha) * c1.x + swz<5>(alpha) * c1.y;
    float s67 = swz<6>(alpha) * c1.z + swz<7>(alpha) * c1.w;
    float s89 = swz<8>(alpha) * c2.x + swz<9>(alpha) * c2.y;
    float sab = swz<10>(alpha) * c2.z + swz<11>(alpha) * c2.w;
    float scd = swz<12>(alpha) * c3.x + swz<13>(alpha) * c3.y;
    float sef = swz<14>(alpha) * c3.z + swz<15>(alpha) * c3.w;
    alpha = ((s01 + s23) + (s45 + s67)) + ((s89 + sab) + (scd + sef));

    if ((k & 3) == 3) {  // renorm every 4 chunks (growth <= 9^4, safe)
      float m = alpha;
      m = fmaxf(m, swz<1>(m));
      m = fmaxf(m, swz<2>(m));
      m = fmaxf(m, swz<4>(m));
      m = fmaxf(m, swz<8>(m));
      float inv = 1.f / m;
      alpha *= inv;
      C += __logf(m);
    }
    if (k + 1 < NCHUNK) { c0 = n0; c1 = n1; c2 = n2; c3 = n3; }
  }

  float s = alpha;
  s += swz<1>(s);
  s += swz<2>(s);
  s += swz<4>(s);
  s += swz<8>(s);
  float result = extra + C + __logf(s) - emit0;

  if (lane == 0) partials[b] = result;
  __threadfence();
  unsigned old = 0;
  if (lane == 0) old = atomicAdd(counter, 1u);
  old = __shfl(old, 0, 64);
  if (old == BB - 1) {  // last block: deterministic fixed-order reduce
    __threadfence();
    float v = partials[lane];
    v += __shfl_xor(v, 1, 64);
    v += __shfl_xor(v, 2, 64);
    v += __shfl_xor(v, 4, 64);
    v += __shfl_xor(v, 8, 64);
    v += __shfl_xor(v, 16, 64);
    v += __shfl_xor(v, 32, 64);
    if (lane == 0) {
      out_val[0] = v;
      *counter = 0u;
    }
  }
}

extern "C" void kernel_launch(void* const* d_in, const int* in_sizes, int n_in,
                              void* d_out, int out_size, void* d_ws,
                              size_t ws_size, hipStream_t stream) {
  const float* inputs = (const float*)d_in[0];
  const int* targets = (const int*)d_in[1];
  const int* seqlen = (const int*)d_in[2];
  const float* W = (const float*)d_in[4];
  const float* bias = (const float*)d_in[5];
  const float* trans = (const float*)d_in[6];
  float* out = (float*)d_out;

  float* mats = (float*)d_ws;                        // 64*32*256 f = 2 MB
  float* scales = mats + (size_t)BB * NCHUNK * 256;  // 2048 f
  float* numblk = scales + (size_t)BB * NCHUNK;      // 512 f
  float* partials = numblk + 512;                    // 64 f
  unsigned* counter = (unsigned*)(partials + BB);    // 1 u32

  fused_kernel<<<512, 256, 0, stream>>>(inputs, W, bias, targets, seqlen,
                                        trans, out + 1, mats, scales, numblk,
                                        counter);
  crf_combine_kernel<<<BB, 64, 0, stream>>>(out + 1, targets, mats, scales,
                                            numblk, partials, counter, out);
}